// Round 13
// baseline (451.397 us; speedup 1.0000x reference)
//
#include <hip/hip_runtime.h>
#include <stdint.h>

// MHA forward: B=4, S=2048, E=1024, H=16, Dh=64, causal, fp32 I/O, bf16 MFMA compute.
//
// Pipeline:
//   1. mha_prep_all: cvt X->Xb, cvt Wo->Wob, transpose Wq/Wk/Wv -> Wt (Wq pre-scaled)
//   2. gemm192 (8-phase, 256x192, odd-phase vmcnt(4), T2 swizzle): QKV = Xb @ Wt^T
//   3. mha_attn6: flash attention, 8-WAVE stripe-pair blocks (2x occupancy, K/V staged
//      once per 8 waves), triple-buffered K/V, 2-deep prefetch, one barrier/tile
//   4. gemm128o (8-phase, 256x128, f32+bias): out = AO @ Wob^T + bo

typedef __bf16 bf16_t;
typedef __bf16 bf16x4 __attribute__((ext_vector_type(4)));
typedef __bf16 bf16x8 __attribute__((ext_vector_type(8)));
typedef float  f32x4  __attribute__((ext_vector_type(4)));
typedef float  f32x16 __attribute__((ext_vector_type(16)));
typedef unsigned int u32;

union V8 { bf16x8 v8; bf16x4 h[2]; u32 w[4]; };

__device__ __forceinline__ void gload_lds16(const void* g, void* l) {
  __builtin_amdgcn_global_load_lds((const __attribute__((address_space(1))) void*)g,
                                   (__attribute__((address_space(3))) void*)l, 16, 0, 0);
}

// ---------------- fused prep ----------------

__global__ __launch_bounds__(256) void mha_prep_all(const float* __restrict__ X,
                                                    const float* __restrict__ Wq,
                                                    const float* __restrict__ Wk,
                                                    const float* __restrict__ Wv,
                                                    const float* __restrict__ Wo,
                                                    bf16_t* __restrict__ Xb,
                                                    bf16_t* __restrict__ Wob,
                                                    bf16_t* __restrict__ Wt) {
  const int bx = blockIdx.x;
  if (bx < 4608) {
    const float* src = (bx < 4096) ? X : Wo;
    bf16_t* dst = (bx < 4096) ? Xb : Wob;
    size_t base = (size_t)((bx < 4096) ? bx : bx - 4096) * 256 + threadIdx.x;
    size_t i = base * 8;
    const float4* p = (const float4*)(src + i);
    float4 a = p[0], b = p[1];
    bf16x8 o;
    o[0] = (__bf16)a.x; o[1] = (__bf16)a.y; o[2] = (__bf16)a.z; o[3] = (__bf16)a.w;
    o[4] = (__bf16)b.x; o[5] = (__bf16)b.y; o[6] = (__bf16)b.z; o[7] = (__bf16)b.w;
    *(bf16x8*)(dst + i) = o;
  } else {
    __shared__ float tile[64][65];
    const int pid = bx - 4608;
    const int e0 = (pid & 15) * 64;
    const int mh = pid >> 4;
    const int mat = mh >> 4, h = mh & 15;
    const float* W = (mat == 0) ? Wq : (mat == 1) ? Wk : Wv;
    const float sc = (mat == 0) ? 0.18033688011112042f : 1.0f;
    #pragma unroll
    for (int i = 0; i < 16; i++) {
      int idx = threadIdx.x + i * 256;
      int er = idx >> 6, d = idx & 63;
      tile[er][d] = W[(size_t)(h * 1024 + e0 + er) * 64 + d];
    }
    __syncthreads();
    #pragma unroll
    for (int i = 0; i < 16; i++) {
      int idx = threadIdx.x + i * 256;
      int dr = idx >> 6, ec = idx & 63;
      Wt[(size_t)(mat * 1024 + h * 64 + dr) * 1024 + e0 + ec] = (bf16_t)(tile[ec][dr] * sc);
    }
  }
}

// ---------------- 8-phase 256x192 GEMM: QKV bf16 = A @ Bt^T ----------------

__global__ __launch_bounds__(512, 2) void gemm192(const bf16_t* __restrict__ A,
                                                  const bf16_t* __restrict__ Bt,
                                                  bf16_t* __restrict__ C,
                                                  int M, int N, int K) {
  __shared__ __align__(16) char lds[131072];
  const int tid = threadIdx.x;
  const int l = tid & 63, w = tid >> 6;
  const int g = l >> 4, lg = l & 15;
  const int wr = w >> 2, wc = w & 3;
  const int bid = blockIdx.x;
  const int nbn = N / 192;
  const int gsw = (bid & 7) * (gridDim.x >> 3) + (bid >> 3);
  const long brow = (long)(gsw / nbn) * 256;
  const long bcol = (long)(gsw % nbn) * 192;

  f32x4 acc[8][3];
  #pragma unroll
  for (int im = 0; im < 8; im++)
    #pragma unroll
    for (int n = 0; n < 3; n++) acc[im][n] = (f32x4){0.f, 0.f, 0.f, 0.f};

  auto stage = [&](const bf16_t* base, long trow, int k0, int region, bool pad) {
    #pragma unroll
    for (int j = 0; j < 2; j++) {
      int p = (tid + j * 512) * 16;
      int row = p >> 6, slot = (p >> 4) & 3;
      int src = slot ^ ((row >> 1) & 3);
      int r2 = (pad && row >= 192) ? row - 192 : row;
      gload_lds16(base + (trow + r2) * (long)K + k0 + src * 8,
                  lds + region + p);
    }
  };

  stage(A,  brow, 0,  0,              false);
  stage(Bt, bcol, 0,  65536,          true);
  stage(A,  brow, 32, 16384,          false);
  stage(Bt, bcol, 32, 65536 + 16384,  true);
  stage(A,  brow, 64, 32768,          false);
  stage(Bt, bcol, 64, 65536 + 32768,  true);
  asm volatile("s_waitcnt vmcnt(4)" ::: "memory");
  __builtin_amdgcn_s_barrier();
  __builtin_amdgcn_sched_barrier(0);

  const int sw = (lg >> 1) & 3;
  const int nIter = K >> 7;
  for (int t = 0; t < nIter; t++) {
    const bool more = (t + 1 < nIter);
    const int kb = t * 128;
    #pragma unroll
    for (int ph = 0; ph < 8; ph++) {
      const int slot = ph >> 2;
      const int kh = (ph >> 1) & 1, mq = ph & 1;
      bf16x8 af[4], bfv[3];
      {
        const char* pA = lds + slot * 32768 + kh * 16384;
        const char* pB = pA + 65536;
        #pragma unroll
        for (int m = 0; m < 4; m++) {
          int wrow = wr * 128 + mq * 64 + m * 16 + lg;
          af[m] = *(const bf16x8*)(pA + wrow * 64 + ((g ^ sw) << 4));
        }
        #pragma unroll
        for (int n = 0; n < 3; n++) {
          int wrow = wc * 48 + n * 16 + lg;
          bfv[n] = *(const bf16x8*)(pB + wrow * 64 + ((g ^ sw) << 4));
        }
      }
      if (ph == 0)      stage(A,  brow, kb + 96,  32768 + 16384, false);
      else if (ph == 1) stage(Bt, bcol, kb + 96,  65536 + 32768 + 16384, true);
      else if (more) {
        if (ph == 2)      stage(A,  brow, kb + 128, 0, false);
        else if (ph == 3) stage(Bt, bcol, kb + 128, 65536, true);
        else if (ph == 4) stage(A,  brow, kb + 160, 16384, false);
        else if (ph == 5) stage(Bt, bcol, kb + 160, 65536 + 16384, true);
        else if (ph == 6) stage(A,  brow, kb + 192, 32768, false);
        else              stage(Bt, bcol, kb + 192, 65536 + 32768, true);
      }
      __builtin_amdgcn_s_barrier();
      asm volatile("s_waitcnt lgkmcnt(0)" ::: "memory");
      __builtin_amdgcn_sched_barrier(0);
      __builtin_amdgcn_s_setprio(1);
      #pragma unroll
      for (int m = 0; m < 4; m++)
        #pragma unroll
        for (int n = 0; n < 3; n++)
          acc[mq * 4 + m][n] =
              __builtin_amdgcn_mfma_f32_16x16x32_bf16(af[m], bfv[n], acc[mq * 4 + m][n], 0, 0, 0);
      __builtin_amdgcn_s_setprio(0);
      __builtin_amdgcn_sched_barrier(0);
      if (ph & 1) {
        if (more) asm volatile("s_waitcnt vmcnt(4)" ::: "memory");
        else if (ph == 1) asm volatile("s_waitcnt vmcnt(0)" ::: "memory");
      }
      __builtin_amdgcn_s_barrier();
      __builtin_amdgcn_sched_barrier(0);
    }
  }

  #pragma unroll
  for (int im = 0; im < 8; im++)
    #pragma unroll
    for (int n = 0; n < 3; n++) {
      long row0 = brow + wr * 128 + im * 16 + g * 4;
      long col  = bcol + wc * 48 + n * 16 + lg;
      #pragma unroll
      for (int r = 0; r < 4; r++)
        C[(row0 + r) * N + col] = (bf16_t)acc[im][n][r];
    }
}

// ---------------- 8-phase 256x128 GEMM, f32+bias epilogue (out-projection) ----------------

__global__ __launch_bounds__(512, 2) void gemm128o(const bf16_t* __restrict__ A,
                                                   const bf16_t* __restrict__ Bt,
                                                   float* __restrict__ C,
                                                   const float* __restrict__ bias,
                                                   int M, int N, int K) {
  __shared__ __align__(16) char lds[131072];
  const int tid = threadIdx.x;
  const int l = tid & 63, w = tid >> 6;
  const int g = l >> 4, lg = l & 15;
  const int wr = w >> 2, wc = w & 3;
  const int bid = blockIdx.x;
  const int nbn = N >> 7;
  const int gsw = (bid & 7) * (gridDim.x >> 3) + (bid >> 3);
  const long brow = (long)(gsw / nbn) * 256;
  const long bcol = (long)(gsw % nbn) * 128;

  f32x4 acc[8][2];
  #pragma unroll
  for (int im = 0; im < 8; im++)
    #pragma unroll
    for (int n = 0; n < 2; n++) acc[im][n] = (f32x4){0.f, 0.f, 0.f, 0.f};

  auto stage = [&](const bf16_t* base, long trow, int k0, int region, bool pad) {
    #pragma unroll
    for (int j = 0; j < 2; j++) {
      int p = (tid + j * 512) * 16;
      int row = p >> 6, slot = (p >> 4) & 3;
      int src = slot ^ ((row >> 1) & 3);
      int r2 = pad ? (row & 127) : row;
      gload_lds16(base + (trow + r2) * (long)K + k0 + src * 8,
                  lds + region + p);
    }
  };

  stage(A,  brow, 0,  0,              false);
  stage(Bt, bcol, 0,  65536,          true);
  stage(A,  brow, 32, 16384,          false);
  stage(Bt, bcol, 32, 65536 + 16384,  true);
  stage(A,  brow, 64, 32768,          false);
  stage(Bt, bcol, 64, 65536 + 32768,  true);
  asm volatile("s_waitcnt vmcnt(4)" ::: "memory");
  __builtin_amdgcn_s_barrier();
  __builtin_amdgcn_sched_barrier(0);

  const int sw = (lg >> 1) & 3;
  const int nIter = K >> 7;
  for (int t = 0; t < nIter; t++) {
    const bool more = (t + 1 < nIter);
    const int kb = t * 128;
    #pragma unroll
    for (int ph = 0; ph < 8; ph++) {
      const int slot = ph >> 2;
      const int kh = (ph >> 1) & 1, mq = ph & 1;
      bf16x8 af[4], bfv[2];
      {
        const char* pA = lds + slot * 32768 + kh * 16384;
        const char* pB = pA + 65536;
        #pragma unroll
        for (int m = 0; m < 4; m++) {
          int wrow = wr * 128 + mq * 64 + m * 16 + lg;
          af[m] = *(const bf16x8*)(pA + wrow * 64 + ((g ^ sw) << 4));
        }
        #pragma unroll
        for (int n = 0; n < 2; n++) {
          int wrow = wc * 32 + n * 16 + lg;
          bfv[n] = *(const bf16x8*)(pB + wrow * 64 + ((g ^ sw) << 4));
        }
      }
      if (ph == 0)      stage(A,  brow, kb + 96,  32768 + 16384, false);
      else if (ph == 1) stage(Bt, bcol, kb + 96,  65536 + 32768 + 16384, true);
      else if (more) {
        if (ph == 2)      stage(A,  brow, kb + 128, 0, false);
        else if (ph == 3) stage(Bt, bcol, kb + 128, 65536, true);
        else if (ph == 4) stage(A,  brow, kb + 160, 16384, false);
        else if (ph == 5) stage(Bt, bcol, kb + 160, 65536 + 16384, true);
        else if (ph == 6) stage(A,  brow, kb + 192, 32768, false);
        else              stage(Bt, bcol, kb + 192, 65536 + 32768, true);
      }
      __builtin_amdgcn_s_barrier();
      asm volatile("s_waitcnt lgkmcnt(0)" ::: "memory");
      __builtin_amdgcn_sched_barrier(0);
      __builtin_amdgcn_s_setprio(1);
      #pragma unroll
      for (int m = 0; m < 4; m++)
        #pragma unroll
        for (int n = 0; n < 2; n++)
          acc[mq * 4 + m][n] =
              __builtin_amdgcn_mfma_f32_16x16x32_bf16(af[m], bfv[n], acc[mq * 4 + m][n], 0, 0, 0);
      __builtin_amdgcn_s_setprio(0);
      __builtin_amdgcn_sched_barrier(0);
      if (ph & 1) {
        if (more) asm volatile("s_waitcnt vmcnt(4)" ::: "memory");
        else if (ph == 1) asm volatile("s_waitcnt vmcnt(0)" ::: "memory");
      }
      __builtin_amdgcn_s_barrier();
      __builtin_amdgcn_sched_barrier(0);
    }
  }

  #pragma unroll
  for (int im = 0; im < 8; im++)
    #pragma unroll
    for (int n = 0; n < 2; n++) {
      long row0 = brow + wr * 128 + im * 16 + g * 4;
      long col  = bcol + wc * 32 + n * 16 + lg;
      float bv = bias[col];
      #pragma unroll
      for (int r = 0; r < 4; r++)
        C[(row0 + r) * N + col] = acc[im][n][r] + bv;
    }
}

// ---------------- flash attention: 8-wave stripe-pair blocks ----------------
// Block = 512 thr (8 waves) owning q-rows [sp*256, sp*256+256) (stripes 2sp, 2sp+1).
// All 8 waves share the K/V tile stream: stage = 1 K-load + 1 V-load per thread
// (HBM fetch and stage instructions HALVED vs 4-wave blocks). Triple-buffered,
// 2-deep prefetch, one barrier per tile, vmcnt(2) ledger (2 loads per stage).
// tmaxw = 4sp + 1 + (w>>1); T = 4sp + 4. Grid 512, heavy-pair-first, XCD-clustered.

__global__ __launch_bounds__(512, 6) void mha_attn6(const bf16_t* __restrict__ QKV,
                                                    bf16_t* __restrict__ AO) {
  __shared__ __align__(16) char smem[49152];  // K[3] @ 0/8K/16K | V[3] @ 24K/32K/40K
  const int tid = threadIdx.x;
  const int l = tid & 63, w = tid >> 6;       // w = 0..7
  const int q31 = l & 31;
  const int hi = l >> 5;
  const int hb = (l >> 4) & 1;
  const int lg = l & 15;

  // decode: XCD-clustered, heavy-pair-first
  const int bid = blockIdx.x;                 // 512 blocks
  const int xcd = bid & 7, ii = bid >> 3;
  const int bh = xcd * 8 + (ii & 7);
  const int sp = 7 - (ii >> 3);               // pair index, heavy first
  const int b = bh >> 4, h = bh & 15;

  const int qw = sp * 256 + w * 32;
  const bf16_t* Qp = QKV + (size_t)b * 2048 * 3072 + h * 64;
  const bf16_t* Kp = Qp + 1024;
  const bf16_t* Vp = Qp + 2048;

  bf16x8 qf[4];
  {
    const bf16_t* qrow = Qp + (size_t)(qw + q31) * 3072 + hi * 8;
    #pragma unroll
    for (int ks = 0; ks < 4; ks++) qf[ks] = *(const bf16x8*)(qrow + ks * 16);
  }

  f32x16 o0, o1, z16;
  #pragma unroll
  for (int r = 0; r < 16; r++) { o0[r] = 0.f; o1[r] = 0.f; z16[r] = 0.f; }
  float lsum = 0.f;

  const int tmaxw = 4 * sp + 1 + (w >> 1);
  const int T = 4 * sp + 4;
  const u32 ldsbase = (u32)(uintptr_t)(__attribute__((address_space(3))) char*)smem;

  u32 vb0[2][4];
  #pragma unroll
  for (int mb = 0; mb < 2; mb++)
    #pragma unroll
    for (int ks = 0; ks < 4; ks++)
      vb0[mb][ks] = ldsbase + 24576u +
                    (u32)(((ks * 4 + 2 * mb + hb) << 9) + hi * 256 + lg * 8);

  // per-thread staging pointers: 512 threads cover K tile (8KB) and V tile (8KB)
  const int krow = tid >> 3, kcb = (tid & 7) * 16;
  const int kscb = kcb ^ ((krow & 7) << 4);
  const int st0 = tid >> 5, qq0 = tid & 31;
  const bf16_t* kp0 = Kp + (size_t)krow * 3072 + (kscb >> 1);
  const bf16_t* vp0 = Vp + (size_t)((st0 >> 2) * 16 + (qq0 >> 1)) * 3072 + (st0 & 3) * 16 + (qq0 & 1) * 8;
  const size_t KVSTEP = (size_t)64 * 3072;

  auto stage = [&](int bi) {
    char* kb = smem + bi * 8192;
    char* vb = smem + 24576 + bi * 8192;
    gload_lds16(kp0, kb + tid * 16);
    gload_lds16(vp0, vb + tid * 16);
    kp0 += KVSTEP; vp0 += KVSTEP;
  };

  // 2-deep prologue: tiles 0 and 1 in flight (T >= 4 always)
  stage(0);
  stage(1);
  int cur3 = 0;
  for (int t = 0; t < T; t++) {
    if (t + 1 < T) {
      asm volatile("s_waitcnt vmcnt(2)" ::: "memory");   // tile t complete; t+1 in flight
    } else {
      asm volatile("s_waitcnt vmcnt(0)" ::: "memory");
    }
    __builtin_amdgcn_sched_barrier(0);
    __builtin_amdgcn_s_barrier();                        // the only barrier per tile
    __builtin_amdgcn_sched_barrier(0);
    if (t + 2 < T) {
      int b2 = cur3 + 2; if (b2 >= 3) b2 -= 3;
      stage(b2);                                         // after barrier: WAR-safe
      __builtin_amdgcn_sched_barrier(0);
    }

    const bool active = (t < tmaxw);
    u32 paw[4][4];
    if (active) {
      f32x16 p0, p1;
      {
        const char* kb = smem + cur3 * 8192;
        const int rb0 = q31 * 128;
        const int swz = (l & 7) << 4;
        __builtin_amdgcn_s_setprio(1);
        {
          int colb = (hi << 4) ^ swz;
          bf16x8 kf0 = *(const bf16x8*)(kb + rb0 + colb);
          bf16x8 kf1 = *(const bf16x8*)(kb + 4096 + rb0 + colb);
          p0 = __builtin_amdgcn_mfma_f32_32x32x16_bf16(kf0, qf[0], z16, 0, 0, 0);
          p1 = __builtin_amdgcn_mfma_f32_32x32x16_bf16(kf1, qf[0], z16, 0, 0, 0);
        }
        #pragma unroll
        for (int ks = 1; ks < 4; ks++) {
          int colb = ((ks << 5) | (hi << 4)) ^ swz;
          bf16x8 kf0 = *(const bf16x8*)(kb + rb0 + colb);
          bf16x8 kf1 = *(const bf16x8*)(kb + 4096 + rb0 + colb);
          p0 = __builtin_amdgcn_mfma_f32_32x32x16_bf16(kf0, qf[ks], p0, 0, 0, 0);
          p1 = __builtin_amdgcn_mfma_f32_32x32x16_bf16(kf1, qf[ks], p1, 0, 0, 0);
        }
        __builtin_amdgcn_s_setprio(0);
      }
      if (t == tmaxw - 1) {
        int q = qw + q31;
        int kvb = t * 64 + 4 * hi;
        #pragma unroll
        for (int r = 0; r < 16; r++) {
          int kv0 = kvb + (r & 3) + 8 * (r >> 2);
          if (kv0 > q) p0[r] = -1e30f;
          if (kv0 + 32 > q) p1[r] = -1e30f;
        }
      }
      #pragma unroll
      for (int r = 0; r < 16; r++) p0[r] = exp2f(p0[r]);
      #pragma unroll
      for (int r = 0; r < 16; r++) p1[r] = exp2f(p1[r]);
      float s8[8];
      #pragma unroll
      for (int r = 0; r < 8; r++)
        s8[r] = (p0[r] + p0[r + 8]) + (p1[r] + p1[r + 8]);
      float rs = ((s8[0] + s8[1]) + (s8[2] + s8[3])) + ((s8[4] + s8[5]) + (s8[6] + s8[7]));
      rs += __shfl_xor(rs, 32);
      lsum += rs;
      #pragma unroll
      for (int gblk = 0; gblk < 4; gblk++) {
        int base = (gblk & 1) * 8;
        float e0 = (gblk < 2) ? p0[base + 0] : p1[base + 0];
        float e1 = (gblk < 2) ? p0[base + 1] : p1[base + 1];
        float e2 = (gblk < 2) ? p0[base + 2] : p1[base + 2];
        float e3 = (gblk < 2) ? p0[base + 3] : p1[base + 3];
        float e4 = (gblk < 2) ? p0[base + 4] : p1[base + 4];
        float e5 = (gblk < 2) ? p0[base + 5] : p1[base + 5];
        float e6 = (gblk < 2) ? p0[base + 6] : p1[base + 6];
        float e7 = (gblk < 2) ? p0[base + 7] : p1[base + 7];
        u32 u0, u1, v0, v1;
        asm("v_cvt_pk_bf16_f32 %0, %1, %2" : "=v"(u0) : "v"(e0), "v"(e1));
        asm("v_cvt_pk_bf16_f32 %0, %1, %2" : "=v"(u1) : "v"(e2), "v"(e3));
        asm("v_cvt_pk_bf16_f32 %0, %1, %2" : "=v"(v0) : "v"(e4), "v"(e5));
        asm("v_cvt_pk_bf16_f32 %0, %1, %2" : "=v"(v1) : "v"(e6), "v"(e7));
        asm("v_permlane32_swap_b32 %0, %1" : "+v"(u0), "+v"(v0));
        asm("v_permlane32_swap_b32 %0, %1" : "+v"(u1), "+v"(v1));
        paw[gblk][0] = u0; paw[gblk][1] = u1; paw[gblk][2] = v0; paw[gblk][3] = v1;
      }
      V8 vf[2][4];
      const u32 boff = (u32)cur3 * 8192u;
      #pragma unroll
      for (int mb = 0; mb < 2; mb++)
        #pragma unroll
        for (int ks = 0; ks < 4; ks++) {
          u32 base = vb0[mb][ks] + boff;
          bf16x4 t0, t1;
          asm volatile("ds_read_b64_tr_b16 %0, %1" : "=v"(t0) : "v"(base));
          asm volatile("ds_read_b64_tr_b16 %0, %1 offset:128" : "=v"(t1) : "v"(base));
          vf[mb][ks].h[0] = t0; vf[mb][ks].h[1] = t1;
        }
      asm volatile("s_waitcnt lgkmcnt(0)" ::: "memory");
      __builtin_amdgcn_sched_barrier(0);
      __builtin_amdgcn_s_setprio(1);
      #pragma unroll
      for (int ks = 0; ks < 4; ks++) {
        V8 pa; pa.w[0] = paw[ks][0]; pa.w[1] = paw[ks][1]; pa.w[2] = paw[ks][2]; pa.w[3] = paw[ks][3];
        o0 = __builtin_amdgcn_mfma_f32_32x32x16_bf16(vf[0][ks].v8, pa.v8, o0, 0, 0, 0);
        o1 = __builtin_amdgcn_mfma_f32_32x32x16_bf16(vf[1][ks].v8, pa.v8, o1, 0, 0, 0);
      }
      __builtin_amdgcn_s_setprio(0);
    }
    cur3 = cur3 + 1; if (cur3 == 3) cur3 = 0;
  }

  // epilogue: per-wave transpose via swizzled LDS (8 waves x 4KB = 32KB)
  float linv = 1.f / lsum;
  __syncthreads();
  bf16_t* ow = (bf16_t*)smem + w * 2048;
  #pragma unroll
  for (int mb = 0; mb < 2; mb++)
    #pragma unroll
    for (int r = 0; r < 16; r += 2) {
      int d = mb * 32 + (r & 3) + 8 * (r >> 2) + 4 * hi;
      float a0 = (mb ? o1[r] : o0[r]) * linv;
      float a1 = (mb ? o1[r + 1] : o0[r + 1]) * linv;
      u32 pk;
      asm("v_cvt_pk_bf16_f32 %0, %1, %2" : "=v"(pk) : "v"(a0), "v"(a1));
      int byteoff = q31 * 128 + ((d * 2) ^ ((q31 & 7) << 4));
      *(u32*)((char*)ow + byteoff) = pk;
    }
  __syncthreads();
  const size_t aorow0 = (size_t)b * 2048 + qw;
  #pragma unroll
  for (int it = 0; it < 4; it++) {
    int idx = it * 64 + l;
    int q = idx >> 3, cc = idx & 7;
    bf16x8 v8 = *(const bf16x8*)((const char*)ow + q * 128 + ((cc * 16) ^ ((q & 7) << 4)));
    *(bf16x8*)(AO + (aorow0 + q) * 1024 + h * 64 + cc * 8) = v8;
  }
}

// ---------------- launch ----------------

extern "C" void kernel_launch(void* const* d_in, const int* in_sizes, int n_in,
                              void* d_out, int out_size, void* d_ws, size_t ws_size,
                              hipStream_t stream) {
  (void)in_sizes; (void)n_in; (void)out_size; (void)ws_size;
  const float* X  = (const float*)d_in[0];
  const float* Wq = (const float*)d_in[1];
  const float* Wk = (const float*)d_in[2];
  const float* Wv = (const float*)d_in[3];
  const float* Wo = (const float*)d_in[4];
  const float* bo = (const float*)d_in[5];
  float* out = (float*)d_out;

  char* ws = (char*)d_ws;
  bf16_t* Xb  = (bf16_t*)ws;                          // 16 MiB  [8192][1024]
  bf16_t* AO  = Xb;                                   // reuse (Xb dead after QKV GEMM)
  bf16_t* Wt  = (bf16_t*)(ws + (16u << 20));          // 6 MiB   [3072][1024]
  bf16_t* Wob = (bf16_t*)(ws + (22u << 20));          // 2 MiB   [1024][1024]
  bf16_t* QKV = (bf16_t*)(ws + (24u << 20));          // 48 MiB  [8192][3072]

  mha_prep_all<<<dim3(5376), dim3(256), 0, stream>>>(X, Wq, Wk, Wv, Wo, Xb, Wob, Wt);
  gemm192<<<dim3(512), dim3(512), 0, stream>>>(Xb, Wt, QKV, 8192, 3072, 1024);
  mha_attn6<<<dim3(512), dim3(512), 0, stream>>>(QKV, AO);
  gemm128o<<<dim3(256), dim3(512), 0, stream>>>(AO, Wob, out, bo, 8192, 1024, 1024);
}

// Round 14
// 166.873 us; speedup vs baseline: 2.7050x; 2.7050x over previous
//
#include <hip/hip_runtime.h>
#include <stdint.h>

// MHA forward: B=4, S=2048, E=1024, H=16, Dh=64, causal, fp32 I/O, bf16 MFMA compute.
//
// Pipeline:
//   1. mha_prep_all: cvt X->Xb, cvt Wo->Wob, transpose Wq/Wk/Wv -> Wt (Wq pre-scaled)
//   2. gemm192 (8-phase, 256x192, odd-phase vmcnt(4), T2 swizzle): QKV = Xb @ Wt^T
//   3. mha_attn6: 8-wave stripe-pair flash attention. R13 ERRATum: launch_bounds(512,6)
//      forced an 85-VGPR cap -> compiler spilled the softmax state to scratch
//      (VGPR=40, FETCH 542MB). Fixed: launch_bounds(512,2) — natural ~70 VGPR,
//      3 blocks/CU by LDS = 24 waves/CU.
//   4. gemm128o (8-phase, 256x128, f32+bias): out = AO @ Wob^T + bo

typedef __bf16 bf16_t;
typedef __bf16 bf16x4 __attribute__((ext_vector_type(4)));
typedef __bf16 bf16x8 __attribute__((ext_vector_type(8)));
typedef float  f32x4  __attribute__((ext_vector_type(4)));
typedef float  f32x16 __attribute__((ext_vector_type(16)));
typedef unsigned int u32;

union V8 { bf16x8 v8; bf16x4 h[2]; u32 w[4]; };

__device__ __forceinline__ void gload_lds16(const void* g, void* l) {
  __builtin_amdgcn_global_load_lds((const __attribute__((address_space(1))) void*)g,
                                   (__attribute__((address_space(3))) void*)l, 16, 0, 0);
}

// ---------------- fused prep ----------------

__global__ __launch_bounds__(256) void mha_prep_all(const float* __restrict__ X,
                                                    const float* __restrict__ Wq,
                                                    const float* __restrict__ Wk,
                                                    const float* __restrict__ Wv,
                                                    const float* __restrict__ Wo,
                                                    bf16_t* __restrict__ Xb,
                                                    bf16_t* __restrict__ Wob,
                                                    bf16_t* __restrict__ Wt) {
  const int bx = blockIdx.x;
  if (bx < 4608) {
    const float* src = (bx < 4096) ? X : Wo;
    bf16_t* dst = (bx < 4096) ? Xb : Wob;
    size_t base = (size_t)((bx < 4096) ? bx : bx - 4096) * 256 + threadIdx.x;
    size_t i = base * 8;
    const float4* p = (const float4*)(src + i);
    float4 a = p[0], b = p[1];
    bf16x8 o;
    o[0] = (__bf16)a.x; o[1] = (__bf16)a.y; o[2] = (__bf16)a.z; o[3] = (__bf16)a.w;
    o[4] = (__bf16)b.x; o[5] = (__bf16)b.y; o[6] = (__bf16)b.z; o[7] = (__bf16)b.w;
    *(bf16x8*)(dst + i) = o;
  } else {
    __shared__ float tile[64][65];
    const int pid = bx - 4608;
    const int e0 = (pid & 15) * 64;
    const int mh = pid >> 4;
    const int mat = mh >> 4, h = mh & 15;
    const float* W = (mat == 0) ? Wq : (mat == 1) ? Wk : Wv;
    const float sc = (mat == 0) ? 0.18033688011112042f : 1.0f;
    #pragma unroll
    for (int i = 0; i < 16; i++) {
      int idx = threadIdx.x + i * 256;
      int er = idx >> 6, d = idx & 63;
      tile[er][d] = W[(size_t)(h * 1024 + e0 + er) * 64 + d];
    }
    __syncthreads();
    #pragma unroll
    for (int i = 0; i < 16; i++) {
      int idx = threadIdx.x + i * 256;
      int dr = idx >> 6, ec = idx & 63;
      Wt[(size_t)(mat * 1024 + h * 64 + dr) * 1024 + e0 + ec] = (bf16_t)(tile[ec][dr] * sc);
    }
  }
}

// ---------------- 8-phase 256x192 GEMM: QKV bf16 = A @ Bt^T ----------------

__global__ __launch_bounds__(512, 2) void gemm192(const bf16_t* __restrict__ A,
                                                  const bf16_t* __restrict__ Bt,
                                                  bf16_t* __restrict__ C,
                                                  int M, int N, int K) {
  __shared__ __align__(16) char lds[131072];
  const int tid = threadIdx.x;
  const int l = tid & 63, w = tid >> 6;
  const int g = l >> 4, lg = l & 15;
  const int wr = w >> 2, wc = w & 3;
  const int bid = blockIdx.x;
  const int nbn = N / 192;
  const int gsw = (bid & 7) * (gridDim.x >> 3) + (bid >> 3);
  const long brow = (long)(gsw / nbn) * 256;
  const long bcol = (long)(gsw % nbn) * 192;

  f32x4 acc[8][3];
  #pragma unroll
  for (int im = 0; im < 8; im++)
    #pragma unroll
    for (int n = 0; n < 3; n++) acc[im][n] = (f32x4){0.f, 0.f, 0.f, 0.f};

  auto stage = [&](const bf16_t* base, long trow, int k0, int region, bool pad) {
    #pragma unroll
    for (int j = 0; j < 2; j++) {
      int p = (tid + j * 512) * 16;
      int row = p >> 6, slot = (p >> 4) & 3;
      int src = slot ^ ((row >> 1) & 3);
      int r2 = (pad && row >= 192) ? row - 192 : row;
      gload_lds16(base + (trow + r2) * (long)K + k0 + src * 8,
                  lds + region + p);
    }
  };

  stage(A,  brow, 0,  0,              false);
  stage(Bt, bcol, 0,  65536,          true);
  stage(A,  brow, 32, 16384,          false);
  stage(Bt, bcol, 32, 65536 + 16384,  true);
  stage(A,  brow, 64, 32768,          false);
  stage(Bt, bcol, 64, 65536 + 32768,  true);
  asm volatile("s_waitcnt vmcnt(4)" ::: "memory");
  __builtin_amdgcn_s_barrier();
  __builtin_amdgcn_sched_barrier(0);

  const int sw = (lg >> 1) & 3;
  const int nIter = K >> 7;
  for (int t = 0; t < nIter; t++) {
    const bool more = (t + 1 < nIter);
    const int kb = t * 128;
    #pragma unroll
    for (int ph = 0; ph < 8; ph++) {
      const int slot = ph >> 2;
      const int kh = (ph >> 1) & 1, mq = ph & 1;
      bf16x8 af[4], bfv[3];
      {
        const char* pA = lds + slot * 32768 + kh * 16384;
        const char* pB = pA + 65536;
        #pragma unroll
        for (int m = 0; m < 4; m++) {
          int wrow = wr * 128 + mq * 64 + m * 16 + lg;
          af[m] = *(const bf16x8*)(pA + wrow * 64 + ((g ^ sw) << 4));
        }
        #pragma unroll
        for (int n = 0; n < 3; n++) {
          int wrow = wc * 48 + n * 16 + lg;
          bfv[n] = *(const bf16x8*)(pB + wrow * 64 + ((g ^ sw) << 4));
        }
      }
      if (ph == 0)      stage(A,  brow, kb + 96,  32768 + 16384, false);
      else if (ph == 1) stage(Bt, bcol, kb + 96,  65536 + 32768 + 16384, true);
      else if (more) {
        if (ph == 2)      stage(A,  brow, kb + 128, 0, false);
        else if (ph == 3) stage(Bt, bcol, kb + 128, 65536, true);
        else if (ph == 4) stage(A,  brow, kb + 160, 16384, false);
        else if (ph == 5) stage(Bt, bcol, kb + 160, 65536 + 16384, true);
        else if (ph == 6) stage(A,  brow, kb + 192, 32768, false);
        else              stage(Bt, bcol, kb + 192, 65536 + 32768, true);
      }
      __builtin_amdgcn_s_barrier();
      asm volatile("s_waitcnt lgkmcnt(0)" ::: "memory");
      __builtin_amdgcn_sched_barrier(0);
      __builtin_amdgcn_s_setprio(1);
      #pragma unroll
      for (int m = 0; m < 4; m++)
        #pragma unroll
        for (int n = 0; n < 3; n++)
          acc[mq * 4 + m][n] =
              __builtin_amdgcn_mfma_f32_16x16x32_bf16(af[m], bfv[n], acc[mq * 4 + m][n], 0, 0, 0);
      __builtin_amdgcn_s_setprio(0);
      __builtin_amdgcn_sched_barrier(0);
      if (ph & 1) {
        if (more) asm volatile("s_waitcnt vmcnt(4)" ::: "memory");
        else if (ph == 1) asm volatile("s_waitcnt vmcnt(0)" ::: "memory");
      }
      __builtin_amdgcn_s_barrier();
      __builtin_amdgcn_sched_barrier(0);
    }
  }

  #pragma unroll
  for (int im = 0; im < 8; im++)
    #pragma unroll
    for (int n = 0; n < 3; n++) {
      long row0 = brow + wr * 128 + im * 16 + g * 4;
      long col  = bcol + wc * 48 + n * 16 + lg;
      #pragma unroll
      for (int r = 0; r < 4; r++)
        C[(row0 + r) * N + col] = (bf16_t)acc[im][n][r];
    }
}

// ---------------- 8-phase 256x128 GEMM, f32+bias epilogue (out-projection) ----------------

__global__ __launch_bounds__(512, 2) void gemm128o(const bf16_t* __restrict__ A,
                                                   const bf16_t* __restrict__ Bt,
                                                   float* __restrict__ C,
                                                   const float* __restrict__ bias,
                                                   int M, int N, int K) {
  __shared__ __align__(16) char lds[131072];
  const int tid = threadIdx.x;
  const int l = tid & 63, w = tid >> 6;
  const int g = l >> 4, lg = l & 15;
  const int wr = w >> 2, wc = w & 3;
  const int bid = blockIdx.x;
  const int nbn = N >> 7;
  const int gsw = (bid & 7) * (gridDim.x >> 3) + (bid >> 3);
  const long brow = (long)(gsw / nbn) * 256;
  const long bcol = (long)(gsw % nbn) * 128;

  f32x4 acc[8][2];
  #pragma unroll
  for (int im = 0; im < 8; im++)
    #pragma unroll
    for (int n = 0; n < 2; n++) acc[im][n] = (f32x4){0.f, 0.f, 0.f, 0.f};

  auto stage = [&](const bf16_t* base, long trow, int k0, int region, bool pad) {
    #pragma unroll
    for (int j = 0; j < 2; j++) {
      int p = (tid + j * 512) * 16;
      int row = p >> 6, slot = (p >> 4) & 3;
      int src = slot ^ ((row >> 1) & 3);
      int r2 = pad ? (row & 127) : row;
      gload_lds16(base + (trow + r2) * (long)K + k0 + src * 8,
                  lds + region + p);
    }
  };

  stage(A,  brow, 0,  0,              false);
  stage(Bt, bcol, 0,  65536,          true);
  stage(A,  brow, 32, 16384,          false);
  stage(Bt, bcol, 32, 65536 + 16384,  true);
  stage(A,  brow, 64, 32768,          false);
  stage(Bt, bcol, 64, 65536 + 32768,  true);
  asm volatile("s_waitcnt vmcnt(4)" ::: "memory");
  __builtin_amdgcn_s_barrier();
  __builtin_amdgcn_sched_barrier(0);

  const int sw = (lg >> 1) & 3;
  const int nIter = K >> 7;
  for (int t = 0; t < nIter; t++) {
    const bool more = (t + 1 < nIter);
    const int kb = t * 128;
    #pragma unroll
    for (int ph = 0; ph < 8; ph++) {
      const int slot = ph >> 2;
      const int kh = (ph >> 1) & 1, mq = ph & 1;
      bf16x8 af[4], bfv[2];
      {
        const char* pA = lds + slot * 32768 + kh * 16384;
        const char* pB = pA + 65536;
        #pragma unroll
        for (int m = 0; m < 4; m++) {
          int wrow = wr * 128 + mq * 64 + m * 16 + lg;
          af[m] = *(const bf16x8*)(pA + wrow * 64 + ((g ^ sw) << 4));
        }
        #pragma unroll
        for (int n = 0; n < 2; n++) {
          int wrow = wc * 32 + n * 16 + lg;
          bfv[n] = *(const bf16x8*)(pB + wrow * 64 + ((g ^ sw) << 4));
        }
      }
      if (ph == 0)      stage(A,  brow, kb + 96,  32768 + 16384, false);
      else if (ph == 1) stage(Bt, bcol, kb + 96,  65536 + 32768 + 16384, true);
      else if (more) {
        if (ph == 2)      stage(A,  brow, kb + 128, 0, false);
        else if (ph == 3) stage(Bt, bcol, kb + 128, 65536, true);
        else if (ph == 4) stage(A,  brow, kb + 160, 16384, false);
        else if (ph == 5) stage(Bt, bcol, kb + 160, 65536 + 16384, true);
        else if (ph == 6) stage(A,  brow, kb + 192, 32768, false);
        else              stage(Bt, bcol, kb + 192, 65536 + 32768, true);
      }
      __builtin_amdgcn_s_barrier();
      asm volatile("s_waitcnt lgkmcnt(0)" ::: "memory");
      __builtin_amdgcn_sched_barrier(0);
      __builtin_amdgcn_s_setprio(1);
      #pragma unroll
      for (int m = 0; m < 4; m++)
        #pragma unroll
        for (int n = 0; n < 2; n++)
          acc[mq * 4 + m][n] =
              __builtin_amdgcn_mfma_f32_16x16x32_bf16(af[m], bfv[n], acc[mq * 4 + m][n], 0, 0, 0);
      __builtin_amdgcn_s_setprio(0);
      __builtin_amdgcn_sched_barrier(0);
      if (ph & 1) {
        if (more) asm volatile("s_waitcnt vmcnt(4)" ::: "memory");
        else if (ph == 1) asm volatile("s_waitcnt vmcnt(0)" ::: "memory");
      }
      __builtin_amdgcn_s_barrier();
      __builtin_amdgcn_sched_barrier(0);
    }
  }

  #pragma unroll
  for (int im = 0; im < 8; im++)
    #pragma unroll
    for (int n = 0; n < 2; n++) {
      long row0 = brow + wr * 128 + im * 16 + g * 4;
      long col  = bcol + wc * 32 + n * 16 + lg;
      float bv = bias[col];
      #pragma unroll
      for (int r = 0; r < 4; r++)
        C[(row0 + r) * N + col] = acc[im][n][r] + bv;
    }
}

// ---------------- flash attention: 8-wave stripe-pair blocks ----------------
// launch_bounds(512, 2): no VGPR cap pressure (R13's (512,6) forced spills).
// Natural occupancy: ~70 VGPR -> LDS-limited 3 blocks/CU = 24 waves/CU.

__global__ __launch_bounds__(512, 2) void mha_attn6(const bf16_t* __restrict__ QKV,
                                                    bf16_t* __restrict__ AO) {
  __shared__ __align__(16) char smem[49152];  // K[3] @ 0/8K/16K | V[3] @ 24K/32K/40K
  const int tid = threadIdx.x;
  const int l = tid & 63, w = tid >> 6;       // w = 0..7
  const int q31 = l & 31;
  const int hi = l >> 5;
  const int hb = (l >> 4) & 1;
  const int lg = l & 15;

  // decode: XCD-clustered, heavy-pair-first
  const int bid = blockIdx.x;                 // 512 blocks
  const int xcd = bid & 7, ii = bid >> 3;
  const int bh = xcd * 8 + (ii & 7);
  const int sp = 7 - (ii >> 3);               // pair index, heavy first
  const int b = bh >> 4, h = bh & 15;

  const int qw = sp * 256 + w * 32;
  const bf16_t* Qp = QKV + (size_t)b * 2048 * 3072 + h * 64;
  const bf16_t* Kp = Qp + 1024;
  const bf16_t* Vp = Qp + 2048;

  bf16x8 qf[4];
  {
    const bf16_t* qrow = Qp + (size_t)(qw + q31) * 3072 + hi * 8;
    #pragma unroll
    for (int ks = 0; ks < 4; ks++) qf[ks] = *(const bf16x8*)(qrow + ks * 16);
  }

  f32x16 o0, o1, z16;
  #pragma unroll
  for (int r = 0; r < 16; r++) { o0[r] = 0.f; o1[r] = 0.f; z16[r] = 0.f; }
  float lsum = 0.f;

  const int tmaxw = 4 * sp + 1 + (w >> 1);
  const int T = 4 * sp + 4;
  const u32 ldsbase = (u32)(uintptr_t)(__attribute__((address_space(3))) char*)smem;

  u32 vb0[2][4];
  #pragma unroll
  for (int mb = 0; mb < 2; mb++)
    #pragma unroll
    for (int ks = 0; ks < 4; ks++)
      vb0[mb][ks] = ldsbase + 24576u +
                    (u32)(((ks * 4 + 2 * mb + hb) << 9) + hi * 256 + lg * 8);

  // per-thread staging pointers: 512 threads cover K tile (8KB) and V tile (8KB)
  const int krow = tid >> 3, kcb = (tid & 7) * 16;
  const int kscb = kcb ^ ((krow & 7) << 4);
  const int st0 = tid >> 5, qq0 = tid & 31;
  const bf16_t* kp0 = Kp + (size_t)krow * 3072 + (kscb >> 1);
  const bf16_t* vp0 = Vp + (size_t)((st0 >> 2) * 16 + (qq0 >> 1)) * 3072 + (st0 & 3) * 16 + (qq0 & 1) * 8;
  const size_t KVSTEP = (size_t)64 * 3072;

  auto stage = [&](int bi) {
    char* kb = smem + bi * 8192;
    char* vb = smem + 24576 + bi * 8192;
    gload_lds16(kp0, kb + tid * 16);
    gload_lds16(vp0, vb + tid * 16);
    kp0 += KVSTEP; vp0 += KVSTEP;
  };

  // 2-deep prologue: tiles 0 and 1 in flight (T >= 4 always)
  stage(0);
  stage(1);
  int cur3 = 0;
  for (int t = 0; t < T; t++) {
    if (t + 1 < T) {
      asm volatile("s_waitcnt vmcnt(2)" ::: "memory");   // tile t complete; t+1 in flight
    } else {
      asm volatile("s_waitcnt vmcnt(0)" ::: "memory");
    }
    __builtin_amdgcn_sched_barrier(0);
    __builtin_amdgcn_s_barrier();                        // the only barrier per tile
    __builtin_amdgcn_sched_barrier(0);
    if (t + 2 < T) {
      int b2 = cur3 + 2; if (b2 >= 3) b2 -= 3;
      stage(b2);                                         // after barrier: WAR-safe
      __builtin_amdgcn_sched_barrier(0);
    }

    const bool active = (t < tmaxw);
    u32 paw[4][4];
    if (active) {
      f32x16 p0, p1;
      {
        const char* kb = smem + cur3 * 8192;
        const int rb0 = q31 * 128;
        const int swz = (l & 7) << 4;
        __builtin_amdgcn_s_setprio(1);
        {
          int colb = (hi << 4) ^ swz;
          bf16x8 kf0 = *(const bf16x8*)(kb + rb0 + colb);
          bf16x8 kf1 = *(const bf16x8*)(kb + 4096 + rb0 + colb);
          p0 = __builtin_amdgcn_mfma_f32_32x32x16_bf16(kf0, qf[0], z16, 0, 0, 0);
          p1 = __builtin_amdgcn_mfma_f32_32x32x16_bf16(kf1, qf[0], z16, 0, 0, 0);
        }
        #pragma unroll
        for (int ks = 1; ks < 4; ks++) {
          int colb = ((ks << 5) | (hi << 4)) ^ swz;
          bf16x8 kf0 = *(const bf16x8*)(kb + rb0 + colb);
          bf16x8 kf1 = *(const bf16x8*)(kb + 4096 + rb0 + colb);
          p0 = __builtin_amdgcn_mfma_f32_32x32x16_bf16(kf0, qf[ks], p0, 0, 0, 0);
          p1 = __builtin_amdgcn_mfma_f32_32x32x16_bf16(kf1, qf[ks], p1, 0, 0, 0);
        }
        __builtin_amdgcn_s_setprio(0);
      }
      if (t == tmaxw - 1) {
        int q = qw + q31;
        int kvb = t * 64 + 4 * hi;
        #pragma unroll
        for (int r = 0; r < 16; r++) {
          int kv0 = kvb + (r & 3) + 8 * (r >> 2);
          if (kv0 > q) p0[r] = -1e30f;
          if (kv0 + 32 > q) p1[r] = -1e30f;
        }
      }
      #pragma unroll
      for (int r = 0; r < 16; r++) p0[r] = exp2f(p0[r]);
      #pragma unroll
      for (int r = 0; r < 16; r++) p1[r] = exp2f(p1[r]);
      float s8[8];
      #pragma unroll
      for (int r = 0; r < 8; r++)
        s8[r] = (p0[r] + p0[r + 8]) + (p1[r] + p1[r + 8]);
      float rs = ((s8[0] + s8[1]) + (s8[2] + s8[3])) + ((s8[4] + s8[5]) + (s8[6] + s8[7]));
      rs += __shfl_xor(rs, 32);
      lsum += rs;
      #pragma unroll
      for (int gblk = 0; gblk < 4; gblk++) {
        int base = (gblk & 1) * 8;
        float e0 = (gblk < 2) ? p0[base + 0] : p1[base + 0];
        float e1 = (gblk < 2) ? p0[base + 1] : p1[base + 1];
        float e2 = (gblk < 2) ? p0[base + 2] : p1[base + 2];
        float e3 = (gblk < 2) ? p0[base + 3] : p1[base + 3];
        float e4 = (gblk < 2) ? p0[base + 4] : p1[base + 4];
        float e5 = (gblk < 2) ? p0[base + 5] : p1[base + 5];
        float e6 = (gblk < 2) ? p0[base + 6] : p1[base + 6];
        float e7 = (gblk < 2) ? p0[base + 7] : p1[base + 7];
        u32 u0, u1, v0, v1;
        asm("v_cvt_pk_bf16_f32 %0, %1, %2" : "=v"(u0) : "v"(e0), "v"(e1));
        asm("v_cvt_pk_bf16_f32 %0, %1, %2" : "=v"(u1) : "v"(e2), "v"(e3));
        asm("v_cvt_pk_bf16_f32 %0, %1, %2" : "=v"(v0) : "v"(e4), "v"(e5));
        asm("v_cvt_pk_bf16_f32 %0, %1, %2" : "=v"(v1) : "v"(e6), "v"(e7));
        asm("v_permlane32_swap_b32 %0, %1" : "+v"(u0), "+v"(v0));
        asm("v_permlane32_swap_b32 %0, %1" : "+v"(u1), "+v"(v1));
        paw[gblk][0] = u0; paw[gblk][1] = u1; paw[gblk][2] = v0; paw[gblk][3] = v1;
      }
      V8 vf[2][4];
      const u32 boff = (u32)cur3 * 8192u;
      #pragma unroll
      for (int mb = 0; mb < 2; mb++)
        #pragma unroll
        for (int ks = 0; ks < 4; ks++) {
          u32 base = vb0[mb][ks] + boff;
          bf16x4 t0, t1;
          asm volatile("ds_read_b64_tr_b16 %0, %1" : "=v"(t0) : "v"(base));
          asm volatile("ds_read_b64_tr_b16 %0, %1 offset:128" : "=v"(t1) : "v"(base));
          vf[mb][ks].h[0] = t0; vf[mb][ks].h[1] = t1;
        }
      asm volatile("s_waitcnt lgkmcnt(0)" ::: "memory");
      __builtin_amdgcn_sched_barrier(0);
      __builtin_amdgcn_s_setprio(1);
      #pragma unroll
      for (int ks = 0; ks < 4; ks++) {
        V8 pa; pa.w[0] = paw[ks][0]; pa.w[1] = paw[ks][1]; pa.w[2] = paw[ks][2]; pa.w[3] = paw[ks][3];
        o0 = __builtin_amdgcn_mfma_f32_32x32x16_bf16(vf[0][ks].v8, pa.v8, o0, 0, 0, 0);
        o1 = __builtin_amdgcn_mfma_f32_32x32x16_bf16(vf[1][ks].v8, pa.v8, o1, 0, 0, 0);
      }
      __builtin_amdgcn_s_setprio(0);
    }
    cur3 = cur3 + 1; if (cur3 == 3) cur3 = 0;
  }

  // epilogue: per-wave transpose via swizzled LDS (8 waves x 4KB = 32KB)
  float linv = 1.f / lsum;
  __syncthreads();
  bf16_t* ow = (bf16_t*)smem + w * 2048;
  #pragma unroll
  for (int mb = 0; mb < 2; mb++)
    #pragma unroll
    for (int r = 0; r < 16; r += 2) {
      int d = mb * 32 + (r & 3) + 8 * (r >> 2) + 4 * hi;
      float a0 = (mb ? o1[r] : o0[r]) * linv;
      float a1 = (mb ? o1[r + 1] : o0[r + 1]) * linv;
      u32 pk;
      asm("v_cvt_pk_bf16_f32 %0, %1, %2" : "=v"(pk) : "v"(a0), "v"(a1));
      int byteoff = q31 * 128 + ((d * 2) ^ ((q31 & 7) << 4));
      *(u32*)((char*)ow + byteoff) = pk;
    }
  __syncthreads();
  const size_t aorow0 = (size_t)b * 2048 + qw;
  #pragma unroll
  for (int it = 0; it < 4; it++) {
    int idx = it * 64 + l;
    int q = idx >> 3, cc = idx & 7;
    bf16x8 v8 = *(const bf16x8*)((const char*)ow + q * 128 + ((cc * 16) ^ ((q & 7) << 4)));
    *(bf16x8*)(AO + (aorow0 + q) * 1024 + h * 64 + cc * 8) = v8;
  }
}

// ---------------- launch ----------------

extern "C" void kernel_launch(void* const* d_in, const int* in_sizes, int n_in,
                              void* d_out, int out_size, void* d_ws, size_t ws_size,
                              hipStream_t stream) {
  (void)in_sizes; (void)n_in; (void)out_size; (void)ws_size;
  const float* X  = (const float*)d_in[0];
  const float* Wq = (const float*)d_in[1];
  const float* Wk = (const float*)d_in[2];
  const float* Wv = (const float*)d_in[3];
  const float* Wo = (const float*)d_in[4];
  const float* bo = (const float*)d_in[5];
  float* out = (float*)d_out;

  char* ws = (char*)d_ws;
  bf16_t* Xb  = (bf16_t*)ws;                          // 16 MiB  [8192][1024]
  bf16_t* AO  = Xb;                                   // reuse (Xb dead after QKV GEMM)
  bf16_t* Wt  = (bf16_t*)(ws + (16u << 20));          // 6 MiB   [3072][1024]
  bf16_t* Wob = (bf16_t*)(ws + (22u << 20));          // 2 MiB   [1024][1024]
  bf16_t* QKV = (bf16_t*)(ws + (24u << 20));          // 48 MiB  [8192][3072]

  mha_prep_all<<<dim3(5376), dim3(256), 0, stream>>>(X, Wq, Wk, Wv, Wo, Xb, Wob, Wt);
  gemm192<<<dim3(512), dim3(512), 0, stream>>>(Xb, Wt, QKV, 8192, 3072, 1024);
  mha_attn6<<<dim3(512), dim3(512), 0, stream>>>(QKV, AO);
  gemm128o<<<dim3(256), dim3(512), 0, stream>>>(AO, Wob, out, bo, 8192, 1024, 1024);
}

// Round 15
// 161.159 us; speedup vs baseline: 2.8010x; 1.0355x over previous
//
#include <hip/hip_runtime.h>
#include <stdint.h>

// MHA forward: B=4, S=2048, E=1024, H=16, Dh=64, causal, fp32 I/O, bf16 MFMA compute.
//
// Pipeline (REVERT to R12 best-known config, measured 161.0 us):
//   1. mha_prep_all: cvt X->Xb, cvt Wo->Wob, transpose Wq/Wk/Wv -> Wt (Wq pre-scaled)
//   2. gemm192 (8-phase, 256x192, odd-phase vmcnt(4), T2 swizzle): QKV = Xb @ Wt^T
//   3. mha_attn5: flash attention, triple-buffered K/V, 2-deep prefetch, 4-wave blocks
//   4. gemm128o (8-phase, 256x128, f32+bias): out = AO @ Wob^T + bo

typedef __bf16 bf16_t;
typedef __bf16 bf16x4 __attribute__((ext_vector_type(4)));
typedef __bf16 bf16x8 __attribute__((ext_vector_type(8)));
typedef float  f32x4  __attribute__((ext_vector_type(4)));
typedef float  f32x16 __attribute__((ext_vector_type(16)));
typedef unsigned int u32;

union V8 { bf16x8 v8; bf16x4 h[2]; u32 w[4]; };

__device__ __forceinline__ void gload_lds16(const void* g, void* l) {
  __builtin_amdgcn_global_load_lds((const __attribute__((address_space(1))) void*)g,
                                   (__attribute__((address_space(3))) void*)l, 16, 0, 0);
}

// ---------------- fused prep ----------------

__global__ __launch_bounds__(256) void mha_prep_all(const float* __restrict__ X,
                                                    const float* __restrict__ Wq,
                                                    const float* __restrict__ Wk,
                                                    const float* __restrict__ Wv,
                                                    const float* __restrict__ Wo,
                                                    bf16_t* __restrict__ Xb,
                                                    bf16_t* __restrict__ Wob,
                                                    bf16_t* __restrict__ Wt) {
  const int bx = blockIdx.x;
  if (bx < 4608) {
    const float* src = (bx < 4096) ? X : Wo;
    bf16_t* dst = (bx < 4096) ? Xb : Wob;
    size_t base = (size_t)((bx < 4096) ? bx : bx - 4096) * 256 + threadIdx.x;
    size_t i = base * 8;
    const float4* p = (const float4*)(src + i);
    float4 a = p[0], b = p[1];
    bf16x8 o;
    o[0] = (__bf16)a.x; o[1] = (__bf16)a.y; o[2] = (__bf16)a.z; o[3] = (__bf16)a.w;
    o[4] = (__bf16)b.x; o[5] = (__bf16)b.y; o[6] = (__bf16)b.z; o[7] = (__bf16)b.w;
    *(bf16x8*)(dst + i) = o;
  } else {
    __shared__ float tile[64][65];
    const int pid = bx - 4608;
    const int e0 = (pid & 15) * 64;
    const int mh = pid >> 4;
    const int mat = mh >> 4, h = mh & 15;
    const float* W = (mat == 0) ? Wq : (mat == 1) ? Wk : Wv;
    const float sc = (mat == 0) ? 0.18033688011112042f : 1.0f;
    #pragma unroll
    for (int i = 0; i < 16; i++) {
      int idx = threadIdx.x + i * 256;
      int er = idx >> 6, d = idx & 63;
      tile[er][d] = W[(size_t)(h * 1024 + e0 + er) * 64 + d];
    }
    __syncthreads();
    #pragma unroll
    for (int i = 0; i < 16; i++) {
      int idx = threadIdx.x + i * 256;
      int dr = idx >> 6, ec = idx & 63;
      Wt[(size_t)(mat * 1024 + h * 64 + dr) * 1024 + e0 + ec] = (bf16_t)(tile[ec][dr] * sc);
    }
  }
}

// ---------------- 8-phase 256x192 GEMM: QKV bf16 = A @ Bt^T ----------------

__global__ __launch_bounds__(512, 2) void gemm192(const bf16_t* __restrict__ A,
                                                  const bf16_t* __restrict__ Bt,
                                                  bf16_t* __restrict__ C,
                                                  int M, int N, int K) {
  __shared__ __align__(16) char lds[131072];
  const int tid = threadIdx.x;
  const int l = tid & 63, w = tid >> 6;
  const int g = l >> 4, lg = l & 15;
  const int wr = w >> 2, wc = w & 3;
  const int bid = blockIdx.x;
  const int nbn = N / 192;
  const int gsw = (bid & 7) * (gridDim.x >> 3) + (bid >> 3);
  const long brow = (long)(gsw / nbn) * 256;
  const long bcol = (long)(gsw % nbn) * 192;

  f32x4 acc[8][3];
  #pragma unroll
  for (int im = 0; im < 8; im++)
    #pragma unroll
    for (int n = 0; n < 3; n++) acc[im][n] = (f32x4){0.f, 0.f, 0.f, 0.f};

  auto stage = [&](const bf16_t* base, long trow, int k0, int region, bool pad) {
    #pragma unroll
    for (int j = 0; j < 2; j++) {
      int p = (tid + j * 512) * 16;
      int row = p >> 6, slot = (p >> 4) & 3;
      int src = slot ^ ((row >> 1) & 3);
      int r2 = (pad && row >= 192) ? row - 192 : row;
      gload_lds16(base + (trow + r2) * (long)K + k0 + src * 8,
                  lds + region + p);
    }
  };

  stage(A,  brow, 0,  0,              false);
  stage(Bt, bcol, 0,  65536,          true);
  stage(A,  brow, 32, 16384,          false);
  stage(Bt, bcol, 32, 65536 + 16384,  true);
  stage(A,  brow, 64, 32768,          false);
  stage(Bt, bcol, 64, 65536 + 32768,  true);
  asm volatile("s_waitcnt vmcnt(4)" ::: "memory");
  __builtin_amdgcn_s_barrier();
  __builtin_amdgcn_sched_barrier(0);

  const int sw = (lg >> 1) & 3;
  const int nIter = K >> 7;
  for (int t = 0; t < nIter; t++) {
    const bool more = (t + 1 < nIter);
    const int kb = t * 128;
    #pragma unroll
    for (int ph = 0; ph < 8; ph++) {
      const int slot = ph >> 2;
      const int kh = (ph >> 1) & 1, mq = ph & 1;
      bf16x8 af[4], bfv[3];
      {
        const char* pA = lds + slot * 32768 + kh * 16384;
        const char* pB = pA + 65536;
        #pragma unroll
        for (int m = 0; m < 4; m++) {
          int wrow = wr * 128 + mq * 64 + m * 16 + lg;
          af[m] = *(const bf16x8*)(pA + wrow * 64 + ((g ^ sw) << 4));
        }
        #pragma unroll
        for (int n = 0; n < 3; n++) {
          int wrow = wc * 48 + n * 16 + lg;
          bfv[n] = *(const bf16x8*)(pB + wrow * 64 + ((g ^ sw) << 4));
        }
      }
      if (ph == 0)      stage(A,  brow, kb + 96,  32768 + 16384, false);
      else if (ph == 1) stage(Bt, bcol, kb + 96,  65536 + 32768 + 16384, true);
      else if (more) {
        if (ph == 2)      stage(A,  brow, kb + 128, 0, false);
        else if (ph == 3) stage(Bt, bcol, kb + 128, 65536, true);
        else if (ph == 4) stage(A,  brow, kb + 160, 16384, false);
        else if (ph == 5) stage(Bt, bcol, kb + 160, 65536 + 16384, true);
        else if (ph == 6) stage(A,  brow, kb + 192, 32768, false);
        else              stage(Bt, bcol, kb + 192, 65536 + 32768, true);
      }
      __builtin_amdgcn_s_barrier();
      asm volatile("s_waitcnt lgkmcnt(0)" ::: "memory");
      __builtin_amdgcn_sched_barrier(0);
      __builtin_amdgcn_s_setprio(1);
      #pragma unroll
      for (int m = 0; m < 4; m++)
        #pragma unroll
        for (int n = 0; n < 3; n++)
          acc[mq * 4 + m][n] =
              __builtin_amdgcn_mfma_f32_16x16x32_bf16(af[m], bfv[n], acc[mq * 4 + m][n], 0, 0, 0);
      __builtin_amdgcn_s_setprio(0);
      __builtin_amdgcn_sched_barrier(0);
      if (ph & 1) {
        if (more) asm volatile("s_waitcnt vmcnt(4)" ::: "memory");
        else if (ph == 1) asm volatile("s_waitcnt vmcnt(0)" ::: "memory");
      }
      __builtin_amdgcn_s_barrier();
      __builtin_amdgcn_sched_barrier(0);
    }
  }

  #pragma unroll
  for (int im = 0; im < 8; im++)
    #pragma unroll
    for (int n = 0; n < 3; n++) {
      long row0 = brow + wr * 128 + im * 16 + g * 4;
      long col  = bcol + wc * 48 + n * 16 + lg;
      #pragma unroll
      for (int r = 0; r < 4; r++)
        C[(row0 + r) * N + col] = (bf16_t)acc[im][n][r];
    }
}

// ---------------- 8-phase 256x128 GEMM, f32+bias epilogue (out-projection) ----------------

__global__ __launch_bounds__(512, 2) void gemm128o(const bf16_t* __restrict__ A,
                                                   const bf16_t* __restrict__ Bt,
                                                   float* __restrict__ C,
                                                   const float* __restrict__ bias,
                                                   int M, int N, int K) {
  __shared__ __align__(16) char lds[131072];
  const int tid = threadIdx.x;
  const int l = tid & 63, w = tid >> 6;
  const int g = l >> 4, lg = l & 15;
  const int wr = w >> 2, wc = w & 3;
  const int bid = blockIdx.x;
  const int nbn = N >> 7;
  const int gsw = (bid & 7) * (gridDim.x >> 3) + (bid >> 3);
  const long brow = (long)(gsw / nbn) * 256;
  const long bcol = (long)(gsw % nbn) * 128;

  f32x4 acc[8][2];
  #pragma unroll
  for (int im = 0; im < 8; im++)
    #pragma unroll
    for (int n = 0; n < 2; n++) acc[im][n] = (f32x4){0.f, 0.f, 0.f, 0.f};

  auto stage = [&](const bf16_t* base, long trow, int k0, int region, bool pad) {
    #pragma unroll
    for (int j = 0; j < 2; j++) {
      int p = (tid + j * 512) * 16;
      int row = p >> 6, slot = (p >> 4) & 3;
      int src = slot ^ ((row >> 1) & 3);
      int r2 = pad ? (row & 127) : row;
      gload_lds16(base + (trow + r2) * (long)K + k0 + src * 8,
                  lds + region + p);
    }
  };

  stage(A,  brow, 0,  0,              false);
  stage(Bt, bcol, 0,  65536,          true);
  stage(A,  brow, 32, 16384,          false);
  stage(Bt, bcol, 32, 65536 + 16384,  true);
  stage(A,  brow, 64, 32768,          false);
  stage(Bt, bcol, 64, 65536 + 32768,  true);
  asm volatile("s_waitcnt vmcnt(4)" ::: "memory");
  __builtin_amdgcn_s_barrier();
  __builtin_amdgcn_sched_barrier(0);

  const int sw = (lg >> 1) & 3;
  const int nIter = K >> 7;
  for (int t = 0; t < nIter; t++) {
    const bool more = (t + 1 < nIter);
    const int kb = t * 128;
    #pragma unroll
    for (int ph = 0; ph < 8; ph++) {
      const int slot = ph >> 2;
      const int kh = (ph >> 1) & 1, mq = ph & 1;
      bf16x8 af[4], bfv[2];
      {
        const char* pA = lds + slot * 32768 + kh * 16384;
        const char* pB = pA + 65536;
        #pragma unroll
        for (int m = 0; m < 4; m++) {
          int wrow = wr * 128 + mq * 64 + m * 16 + lg;
          af[m] = *(const bf16x8*)(pA + wrow * 64 + ((g ^ sw) << 4));
        }
        #pragma unroll
        for (int n = 0; n < 2; n++) {
          int wrow = wc * 32 + n * 16 + lg;
          bfv[n] = *(const bf16x8*)(pB + wrow * 64 + ((g ^ sw) << 4));
        }
      }
      if (ph == 0)      stage(A,  brow, kb + 96,  32768 + 16384, false);
      else if (ph == 1) stage(Bt, bcol, kb + 96,  65536 + 32768 + 16384, true);
      else if (more) {
        if (ph == 2)      stage(A,  brow, kb + 128, 0, false);
        else if (ph == 3) stage(Bt, bcol, kb + 128, 65536, true);
        else if (ph == 4) stage(A,  brow, kb + 160, 16384, false);
        else if (ph == 5) stage(Bt, bcol, kb + 160, 65536 + 16384, true);
        else if (ph == 6) stage(A,  brow, kb + 192, 32768, false);
        else              stage(Bt, bcol, kb + 192, 65536 + 32768, true);
      }
      __builtin_amdgcn_s_barrier();
      asm volatile("s_waitcnt lgkmcnt(0)" ::: "memory");
      __builtin_amdgcn_sched_barrier(0);
      __builtin_amdgcn_s_setprio(1);
      #pragma unroll
      for (int m = 0; m < 4; m++)
        #pragma unroll
        for (int n = 0; n < 2; n++)
          acc[mq * 4 + m][n] =
              __builtin_amdgcn_mfma_f32_16x16x32_bf16(af[m], bfv[n], acc[mq * 4 + m][n], 0, 0, 0);
      __builtin_amdgcn_s_setprio(0);
      __builtin_amdgcn_sched_barrier(0);
      if (ph & 1) {
        if (more) asm volatile("s_waitcnt vmcnt(4)" ::: "memory");
        else if (ph == 1) asm volatile("s_waitcnt vmcnt(0)" ::: "memory");
      }
      __builtin_amdgcn_s_barrier();
      __builtin_amdgcn_sched_barrier(0);
    }
  }

  #pragma unroll
  for (int im = 0; im < 8; im++)
    #pragma unroll
    for (int n = 0; n < 2; n++) {
      long row0 = brow + wr * 128 + im * 16 + g * 4;
      long col  = bcol + wc * 32 + n * 16 + lg;
      float bv = bias[col];
      #pragma unroll
      for (int r = 0; r < 4; r++)
        C[(row0 + r) * N + col] = acc[im][n][r] + bv;
    }
}

// ---------------- flash attention: triple-buffered K/V, 2-deep prefetch ----------------
// (R12 configuration — best measured: 69.9 us)

__global__ __launch_bounds__(256, 3) void mha_attn5(const bf16_t* __restrict__ QKV,
                                                    bf16_t* __restrict__ AO) {
  __shared__ __align__(16) char smem[49152];  // K[3] @ 0/8K/16K | V[3] @ 24K/32K/40K
  const int tid = threadIdx.x;
  const int l = tid & 63, w = tid >> 6;
  const int q31 = l & 31;
  const int hi = l >> 5;
  const int hb = (l >> 4) & 1;
  const int lg = l & 15;

  const int bid = blockIdx.x;
  const int xcd = bid & 7, ii = bid >> 3;
  const int bh = xcd * 8 + (ii & 7);
  const int stripe = 15 - (ii >> 3);
  const int b = bh >> 4, h = bh & 15;

  const int qw = stripe * 128 + w * 32;
  const bf16_t* Qp = QKV + (size_t)b * 2048 * 3072 + h * 64;
  const bf16_t* Kp = Qp + 1024;
  const bf16_t* Vp = Qp + 2048;

  bf16x8 qf[4];
  {
    const bf16_t* qrow = Qp + (size_t)(qw + q31) * 3072 + hi * 8;
    #pragma unroll
    for (int ks = 0; ks < 4; ks++) qf[ks] = *(const bf16x8*)(qrow + ks * 16);
  }

  f32x16 o0, o1, z16;
  #pragma unroll
  for (int r = 0; r < 16; r++) { o0[r] = 0.f; o1[r] = 0.f; z16[r] = 0.f; }
  float lsum = 0.f;

  const int tmaxw = 2 * stripe + 1 + (w >> 1);
  const int T = 2 * stripe + 2;
  const u32 ldsbase = (u32)(uintptr_t)(__attribute__((address_space(3))) char*)smem;

  u32 vb0[2][4];
  #pragma unroll
  for (int mb = 0; mb < 2; mb++)
    #pragma unroll
    for (int ks = 0; ks < 4; ks++)
      vb0[mb][ks] = ldsbase + 24576u +
                    (u32)(((ks * 4 + 2 * mb + hb) << 9) + hi * 256 + lg * 8);

  const int krow = tid >> 3, kcb = (tid & 7) * 16;
  const int kscb = kcb ^ ((krow & 7) << 4);
  const int st0 = tid >> 5, qq0 = tid & 31;
  const int st1 = (tid + 256) >> 5;
  const bf16_t* kp0 = Kp + (size_t)krow * 3072 + (kscb >> 1);
  const bf16_t* kp1 = kp0 + (size_t)32 * 3072;
  const bf16_t* vp0 = Vp + (size_t)((st0 >> 2) * 16 + (qq0 >> 1)) * 3072 + (st0 & 3) * 16 + (qq0 & 1) * 8;
  const bf16_t* vp1 = Vp + (size_t)((st1 >> 2) * 16 + (qq0 >> 1)) * 3072 + (st1 & 3) * 16 + (qq0 & 1) * 8;
  const size_t KVSTEP = (size_t)64 * 3072;

  auto stage = [&](int bi) {
    char* kb = smem + bi * 8192;
    char* vb = smem + 24576 + bi * 8192;
    gload_lds16(kp0, kb + tid * 16);
    gload_lds16(vp0, vb + tid * 16);
    gload_lds16(kp1, kb + (tid + 256) * 16);
    gload_lds16(vp1, vb + (tid + 256) * 16);
    kp0 += KVSTEP; kp1 += KVSTEP; vp0 += KVSTEP; vp1 += KVSTEP;
  };

  // 2-deep prologue: tiles 0 and 1 in flight (T >= 2 always)
  stage(0);
  stage(1);
  int cur3 = 0;
  for (int t = 0; t < T; t++) {
    if (t + 1 < T) {
      asm volatile("s_waitcnt vmcnt(4)" ::: "memory");   // tile t complete; t+1 in flight
    } else {
      asm volatile("s_waitcnt vmcnt(0)" ::: "memory");
    }
    __builtin_amdgcn_sched_barrier(0);
    __builtin_amdgcn_s_barrier();                        // the only barrier per tile
    __builtin_amdgcn_sched_barrier(0);
    if (t + 2 < T) {
      int b2 = cur3 + 2; if (b2 >= 3) b2 -= 3;
      stage(b2);                                         // after barrier: WAR-safe
      __builtin_amdgcn_sched_barrier(0);
    }

    const bool active = (t < tmaxw);
    u32 paw[4][4];
    if (active) {
      f32x16 p0, p1;
      {
        const char* kb = smem + cur3 * 8192;
        const int rb0 = q31 * 128;
        const int swz = (l & 7) << 4;
        __builtin_amdgcn_s_setprio(1);
        {
          int colb = (hi << 4) ^ swz;
          bf16x8 kf0 = *(const bf16x8*)(kb + rb0 + colb);
          bf16x8 kf1 = *(const bf16x8*)(kb + 4096 + rb0 + colb);
          p0 = __builtin_amdgcn_mfma_f32_32x32x16_bf16(kf0, qf[0], z16, 0, 0, 0);
          p1 = __builtin_amdgcn_mfma_f32_32x32x16_bf16(kf1, qf[0], z16, 0, 0, 0);
        }
        #pragma unroll
        for (int ks = 1; ks < 4; ks++) {
          int colb = ((ks << 5) | (hi << 4)) ^ swz;
          bf16x8 kf0 = *(const bf16x8*)(kb + rb0 + colb);
          bf16x8 kf1 = *(const bf16x8*)(kb + 4096 + rb0 + colb);
          p0 = __builtin_amdgcn_mfma_f32_32x32x16_bf16(kf0, qf[ks], p0, 0, 0, 0);
          p1 = __builtin_amdgcn_mfma_f32_32x32x16_bf16(kf1, qf[ks], p1, 0, 0, 0);
        }
        __builtin_amdgcn_s_setprio(0);
      }
      if (t == tmaxw - 1) {
        int q = qw + q31;
        int kvb = t * 64 + 4 * hi;
        #pragma unroll
        for (int r = 0; r < 16; r++) {
          int kv0 = kvb + (r & 3) + 8 * (r >> 2);
          if (kv0 > q) p0[r] = -1e30f;
          if (kv0 + 32 > q) p1[r] = -1e30f;
        }
      }
      #pragma unroll
      for (int r = 0; r < 16; r++) p0[r] = exp2f(p0[r]);
      #pragma unroll
      for (int r = 0; r < 16; r++) p1[r] = exp2f(p1[r]);
      float s8[8];
      #pragma unroll
      for (int r = 0; r < 8; r++)
        s8[r] = (p0[r] + p0[r + 8]) + (p1[r] + p1[r + 8]);
      float rs = ((s8[0] + s8[1]) + (s8[2] + s8[3])) + ((s8[4] + s8[5]) + (s8[6] + s8[7]));
      rs += __shfl_xor(rs, 32);
      lsum += rs;
      #pragma unroll
      for (int gblk = 0; gblk < 4; gblk++) {
        int base = (gblk & 1) * 8;
        float e0 = (gblk < 2) ? p0[base + 0] : p1[base + 0];
        float e1 = (gblk < 2) ? p0[base + 1] : p1[base + 1];
        float e2 = (gblk < 2) ? p0[base + 2] : p1[base + 2];
        float e3 = (gblk < 2) ? p0[base + 3] : p1[base + 3];
        float e4 = (gblk < 2) ? p0[base + 4] : p1[base + 4];
        float e5 = (gblk < 2) ? p0[base + 5] : p1[base + 5];
        float e6 = (gblk < 2) ? p0[base + 6] : p1[base + 6];
        float e7 = (gblk < 2) ? p0[base + 7] : p1[base + 7];
        u32 u0, u1, v0, v1;
        asm("v_cvt_pk_bf16_f32 %0, %1, %2" : "=v"(u0) : "v"(e0), "v"(e1));
        asm("v_cvt_pk_bf16_f32 %0, %1, %2" : "=v"(u1) : "v"(e2), "v"(e3));
        asm("v_cvt_pk_bf16_f32 %0, %1, %2" : "=v"(v0) : "v"(e4), "v"(e5));
        asm("v_cvt_pk_bf16_f32 %0, %1, %2" : "=v"(v1) : "v"(e6), "v"(e7));
        asm("v_permlane32_swap_b32 %0, %1" : "+v"(u0), "+v"(v0));
        asm("v_permlane32_swap_b32 %0, %1" : "+v"(u1), "+v"(v1));
        paw[gblk][0] = u0; paw[gblk][1] = u1; paw[gblk][2] = v0; paw[gblk][3] = v1;
      }
      V8 vf[2][4];
      const u32 boff = (u32)cur3 * 8192u;
      #pragma unroll
      for (int mb = 0; mb < 2; mb++)
        #pragma unroll
        for (int ks = 0; ks < 4; ks++) {
          u32 base = vb0[mb][ks] + boff;
          bf16x4 t0, t1;
          asm volatile("ds_read_b64_tr_b16 %0, %1" : "=v"(t0) : "v"(base));
          asm volatile("ds_read_b64_tr_b16 %0, %1 offset:128" : "=v"(t1) : "v"(base));
          vf[mb][ks].h[0] = t0; vf[mb][ks].h[1] = t1;
        }
      asm volatile("s_waitcnt lgkmcnt(0)" ::: "memory");
      __builtin_amdgcn_sched_barrier(0);
      __builtin_amdgcn_s_setprio(1);
      #pragma unroll
      for (int ks = 0; ks < 4; ks++) {
        V8 pa; pa.w[0] = paw[ks][0]; pa.w[1] = paw[ks][1]; pa.w[2] = paw[ks][2]; pa.w[3] = paw[ks][3];
        o0 = __builtin_amdgcn_mfma_f32_32x32x16_bf16(vf[0][ks].v8, pa.v8, o0, 0, 0, 0);
        o1 = __builtin_amdgcn_mfma_f32_32x32x16_bf16(vf[1][ks].v8, pa.v8, o1, 0, 0, 0);
      }
      __builtin_amdgcn_s_setprio(0);
    }
    cur3 = cur3 + 1; if (cur3 == 3) cur3 = 0;
  }

  // epilogue
  float linv = 1.f / lsum;
  __syncthreads();
  bf16_t* ow = (bf16_t*)smem + w * 2048;
  #pragma unroll
  for (int mb = 0; mb < 2; mb++)
    #pragma unroll
    for (int r = 0; r < 16; r += 2) {
      int d = mb * 32 + (r & 3) + 8 * (r >> 2) + 4 * hi;
      float a0 = (mb ? o1[r] : o0[r]) * linv;
      float a1 = (mb ? o1[r + 1] : o0[r + 1]) * linv;
      u32 pk;
      asm("v_cvt_pk_bf16_f32 %0, %1, %2" : "=v"(pk) : "v"(a0), "v"(a1));
      int byteoff = q31 * 128 + ((d * 2) ^ ((q31 & 7) << 4));
      *(u32*)((char*)ow + byteoff) = pk;
    }
  __syncthreads();
  const size_t aorow0 = (size_t)b * 2048 + qw;
  #pragma unroll
  for (int it = 0; it < 4; it++) {
    int idx = it * 64 + l;
    int q = idx >> 3, cc = idx & 7;
    bf16x8 v8 = *(const bf16x8*)((const char*)ow + q * 128 + ((cc * 16) ^ ((q & 7) << 4)));
    *(bf16x8*)(AO + (aorow0 + q) * 1024 + h * 64 + cc * 8) = v8;
  }
}

// ---------------- launch ----------------

extern "C" void kernel_launch(void* const* d_in, const int* in_sizes, int n_in,
                              void* d_out, int out_size, void* d_ws, size_t ws_size,
                              hipStream_t stream) {
  (void)in_sizes; (void)n_in; (void)out_size; (void)ws_size;
  const float* X  = (const float*)d_in[0];
  const float* Wq = (const float*)d_in[1];
  const float* Wk = (const float*)d_in[2];
  const float* Wv = (const float*)d_in[3];
  const float* Wo = (const float*)d_in[4];
  const float* bo = (const float*)d_in[5];
  float* out = (float*)d_out;

  char* ws = (char*)d_ws;
  bf16_t* Xb  = (bf16_t*)ws;                          // 16 MiB  [8192][1024]
  bf16_t* AO  = Xb;                                   // reuse (Xb dead after QKV GEMM)
  bf16_t* Wt  = (bf16_t*)(ws + (16u << 20));          // 6 MiB   [3072][1024]
  bf16_t* Wob = (bf16_t*)(ws + (22u << 20));          // 2 MiB   [1024][1024]
  bf16_t* QKV = (bf16_t*)(ws + (24u << 20));          // 48 MiB  [8192][3072]

  mha_prep_all<<<dim3(5376), dim3(256), 0, stream>>>(X, Wq, Wk, Wv, Wo, Xb, Wob, Wt);
  gemm192<<<dim3(512), dim3(512), 0, stream>>>(Xb, Wt, QKV, 8192, 3072, 1024);
  mha_attn5<<<dim3(1024), dim3(256), 0, stream>>>(QKV, AO);
  gemm128o<<<dim3(256), dim3(512), 0, stream>>>(AO, Wob, out, bo, 8192, 1024, 1024);
}